// Round 1
// baseline (2306.576 us; speedup 1.0000x reference)
//
#include <hip/hip_runtime.h>
#include <cstdint>
#include <cstddef>

#define N_USERS 100000
#define N_ITEMS 50000
#define DIM     64
#define IMG_D   1024
#define TXT_D   384
#define N_EDGES 2000000
#define N_COMB  (N_USERS + N_ITEMS)

// d_out layout (floats), concatenated in reference return order
#define OFF_UOUT 0
#define OFF_IOUT (N_USERS * DIM)            // 6,400,000
#define OFF_IIT  (OFF_IOUT + N_ITEMS * DIM) // 9,600,000
#define OFF_TIT  (OFF_IIT + N_ITEMS * DIM)  // 12,800,000
#define OFF_IUS  (OFF_TIT + N_ITEMS * DIM)  // 16,000,000
#define OFF_TUS  (OFF_IUS + N_USERS * DIM)  // 22,400,000

__device__ __forceinline__ float wave_sum64(float v) {
#pragma unroll
  for (int off = 32; off; off >>= 1) v += __shfl_xor(v, off, 64);
  return v;
}

// ---------------- CSR build ----------------
__global__ __launch_bounds__(256) void hist_kernel(const int* __restrict__ eu,
                                                   const int* __restrict__ ei,
                                                   int* __restrict__ cu, int* __restrict__ ci) {
  const int i = blockIdx.x * 256 + threadIdx.x;
  if (i < N_EDGES) {
    atomicAdd(&cu[eu[i]], 1);
    atomicAdd(&ci[ei[i]], 1);
  }
}

__global__ __launch_bounds__(1024) void scan_kernel(const int* __restrict__ counts,
                                                    int* __restrict__ rs, int* __restrict__ cur,
                                                    int n) {
  __shared__ int part[1024];
  const int t = threadIdx.x;
  const int chunk = (n + 1023) >> 10;
  const int b = t * chunk;
  const int e = min(b + chunk, n);
  int s = 0;
  for (int j = b; j < e; ++j) s += counts[j];
  part[t] = s;
  __syncthreads();
  for (int off = 1; off < 1024; off <<= 1) {
    const int add = (t >= off) ? part[t - off] : 0;
    __syncthreads();
    part[t] += add;
    __syncthreads();
  }
  int run = (t == 0) ? 0 : part[t - 1];
  for (int j = b; j < e; ++j) {
    rs[j] = run;
    cur[j] = run;
    run += counts[j];
  }
  if (t == 1023) rs[n] = part[1023];
}

__global__ __launch_bounds__(256) void fill_kernel(
    const int* __restrict__ eu, const int* __restrict__ ei,
    const float* __restrict__ vui, const float* __restrict__ viu,
    int* __restrict__ cur_u, int* __restrict__ cur_i,
    int* __restrict__ col_u, float* __restrict__ w_u,
    int* __restrict__ col_i, float* __restrict__ w_i) {
  const int i = blockIdx.x * 256 + threadIdx.x;
  if (i < N_EDGES) {
    const int u = eu[i], it = ei[i];
    const int p = atomicAdd(&cur_u[u], 1);
    col_u[p] = it;
    w_u[p] = vui[i];
    const int q = atomicAdd(&cur_i[it], 1);
    col_i[q] = u;
    w_i[q] = viu[i];
  }
}

// ---------------- fused dense GEMM (image + text) ----------------
// thread = one row, acc[64] in VGPRs; W reads are lane-uniform -> scalar loads.
// K split across wave-pairs, combined through padded LDS.
__global__ __launch_bounds__(256) void gemm_kernel(
    const float* __restrict__ Ximg, const float* __restrict__ Wimg, const float* __restrict__ bimg,
    const float* __restrict__ Xtxt, const float* __restrict__ Wtxt, const float* __restrict__ btxt,
    float* __restrict__ feat128) {
  const int nblk_img = (N_ITEMS + 127) / 128;  // 391
  int b = blockIdx.x;
  const float* X;
  const float* W;
  const float* bias;
  int K, c0;
  if (b < nblk_img) {
    X = Ximg; W = Wimg; bias = bimg; K = IMG_D; c0 = 0;
  } else {
    b -= nblk_img;
    X = Xtxt; W = Wtxt; bias = btxt; K = TXT_D; c0 = 64;
  }
  const int row0 = b * 128;
  const int lane = threadIdx.x & 63;
  const int wv = threadIdx.x >> 6;
  const int grp = wv >> 1;  // row group (0..1)
  const int kh = wv & 1;    // k half
  const int row = row0 + grp * 64 + lane;

  float acc[64];
#pragma unroll
  for (int d = 0; d < 64; ++d) acc[d] = 0.f;

  const int khalf = K >> 1;
  const int k0 = kh * khalf, k1 = k0 + khalf;
  if (row < N_ITEMS) {
    const float* __restrict__ xr = X + (size_t)row * K;
    for (int k = k0; k < k1; k += 4) {
      const float4 xv = *reinterpret_cast<const float4*>(xr + k);
      const float* __restrict__ wk = W + (size_t)k * 64;
#pragma unroll
      for (int d = 0; d < 64; ++d) acc[d] = fmaf(xv.x, wk[d], acc[d]);
#pragma unroll
      for (int d = 0; d < 64; ++d) acc[d] = fmaf(xv.y, wk[d + 64], acc[d]);
#pragma unroll
      for (int d = 0; d < 64; ++d) acc[d] = fmaf(xv.z, wk[d + 128], acc[d]);
#pragma unroll
      for (int d = 0; d < 64; ++d) acc[d] = fmaf(xv.w, wk[d + 192], acc[d]);
    }
  }

  // combine k-halves via LDS; layout L[d*65 + row_in_group] (pad 65 -> conflict-free)
  __shared__ float lds[2][64 * 65];
  float* __restrict__ L = lds[grp];
  if (kh == 0) {
#pragma unroll
    for (int d = 0; d < 64; ++d) L[d * 65 + lane] = acc[d];
  }
  __syncthreads();
  if (kh == 1) {
#pragma unroll
    for (int d = 0; d < 64; ++d) L[d * 65 + lane] += acc[d];
  }
  __syncthreads();

  const float bv = bias[lane];
  for (int rr = wv; rr < 128; rr += 4) {
    const int grow = row0 + rr;
    if (grow < N_ITEMS) {
      const float v = lds[rr >> 6][lane * 65 + (rr & 63)] + bv;
      feat128[(size_t)grow * 128 + c0 + lane] = v;  // lane = output dim -> coalesced
    }
  }
}

// ---------------- normalization statistics ----------------
__global__ __launch_bounds__(256) void stats_kernel(const float* __restrict__ ue,
                                                    const float* __restrict__ ie,
                                                    float* __restrict__ stats) {
  const int t = threadIdx.x;
  const int lane = t & 63;
  float cs = 0.f, ss = 0.f;
  const size_t total = (size_t)N_COMB * DIM;
  const size_t ubound = (size_t)N_USERS * DIM;
  const size_t stride = (size_t)gridDim.x * blockDim.x;  // multiple of 64 -> column stays fixed
  for (size_t i = (size_t)blockIdx.x * blockDim.x + t; i < total; i += stride) {
    const float v = (i < ubound) ? ue[i] : ie[i - ubound];
    cs += v;
    ss += v * v;
  }
  ss = wave_sum64(ss);
  __shared__ float lcol[4][64];
  __shared__ float lss[4];
  const int wv = t >> 6;
  lcol[wv][lane] = cs;
  if (lane == 0) lss[wv] = ss;
  __syncthreads();
  if (wv == 0) {
    const float c = lcol[0][lane] + lcol[1][lane] + lcol[2][lane] + lcol[3][lane];
    atomicAdd(&stats[lane], c);
    if (lane == 0) atomicAdd(&stats[64], lss[0] + lss[1] + lss[2] + lss[3]);
  }
}

__global__ void finalize_kernel(float* __restrict__ stats) {
  const int d = threadIdx.x;  // 64 threads
  const float ssum = stats[64];
  const float m = stats[d] / (float)N_COMB;
  const float m2sum = wave_sum64(m * m);
  const float tot = ssum - (float)N_COMB * m2sum;
  const float rnm = sqrtf(tot / (float)N_COMB + 1e-6f);
  stats[d] = m;
  if (d == 0) stats[64] = 1.f / rnm;
}

__global__ __launch_bounds__(256) void normalize_kernel(
    const float* __restrict__ ue, const float* __restrict__ ie, const float* __restrict__ stats,
    float* __restrict__ uacc, float* __restrict__ iacc, float* __restrict__ i0) {
  const int lane = threadIdx.x & 63;
  const float m = stats[lane];
  const float inv = stats[64];
  const size_t total = (size_t)N_COMB * DIM;
  const size_t ubound = (size_t)N_USERS * DIM;
  const size_t stride = (size_t)gridDim.x * blockDim.x;
  for (size_t i = (size_t)blockIdx.x * blockDim.x + threadIdx.x; i < total; i += stride) {
    if (i < ubound) {
      uacc[i] = (ue[i] - m) * inv;
    } else {
      const size_t j = i - ubound;
      const float v = (ie[j] - m) * inv;
      iacc[j] = v;
      i0[j] = v;
    }
  }
}

// ---------------- SPMM (CSR gather, wave per row, lane = dim) ----------------
__global__ __launch_bounds__(256) void spmm64_kernel(
    const int* __restrict__ rs, const int* __restrict__ col, const float* __restrict__ w,
    const float* __restrict__ X, float* __restrict__ out, float* __restrict__ acc, int nrows) {
  const int lane = threadIdx.x & 63;
  const int wv = __builtin_amdgcn_readfirstlane(threadIdx.x >> 6);
  const int r = blockIdx.x * 4 + wv;
  if (r >= nrows) return;
  const int s = rs[r], e = rs[r + 1];
  float a = 0.f;
  int k = s;
  for (; k + 4 <= e; k += 4) {
    const int c0 = col[k], c1 = col[k + 1], c2 = col[k + 2], c3 = col[k + 3];
    const float w0 = w[k], w1 = w[k + 1], w2 = w[k + 2], w3 = w[k + 3];
    const float x0 = X[(size_t)c0 * 64 + lane];
    const float x1 = X[(size_t)c1 * 64 + lane];
    const float x2 = X[(size_t)c2 * 64 + lane];
    const float x3 = X[(size_t)c3 * 64 + lane];
    a = fmaf(w0, x0, a);
    a = fmaf(w1, x1, a);
    a = fmaf(w2, x2, a);
    a = fmaf(w3, x3, a);
  }
  for (; k < e; ++k) a = fmaf(w[k], X[(size_t)col[k] * 64 + lane], a);
  const size_t o = (size_t)r * 64 + lane;
  if (out) out[o] = a;
  if (acc) acc[o] += a;
}

__global__ __launch_bounds__(256) void spmm_dual_kernel(
    const int* __restrict__ rs, const int* __restrict__ col, const float* __restrict__ w,
    const float* __restrict__ XA, int sA, const float* __restrict__ XB, int sB,
    float* __restrict__ outA, float* __restrict__ outB, int nrows) {
  const int lane = threadIdx.x & 63;
  const int wv = __builtin_amdgcn_readfirstlane(threadIdx.x >> 6);
  const int r = blockIdx.x * 4 + wv;
  if (r >= nrows) return;
  const int s = rs[r], e = rs[r + 1];
  float a = 0.f, bq = 0.f;
  int k = s;
  for (; k + 2 <= e; k += 2) {
    const int c0 = col[k], c1 = col[k + 1];
    const float w0 = w[k], w1 = w[k + 1];
    const float xa0 = XA[(size_t)c0 * sA + lane];
    const float xb0 = XB[(size_t)c0 * sB + lane];
    const float xa1 = XA[(size_t)c1 * sA + lane];
    const float xb1 = XB[(size_t)c1 * sB + lane];
    a = fmaf(w0, xa0, a);
    bq = fmaf(w0, xb0, bq);
    a = fmaf(w1, xa1, a);
    bq = fmaf(w1, xb1, bq);
  }
  for (; k < e; ++k) {
    const int c = col[k];
    const float wk = w[k];
    a = fmaf(wk, XA[(size_t)c * sA + lane], a);
    bq = fmaf(wk, XB[(size_t)c * sB + lane], bq);
  }
  const size_t o = (size_t)r * 64 + lane;
  outA[o] = a;
  outB[o] = bq;
}

// ---------------- epilogue: out = acc/3 + 0.55*l2norm(P) + 0.55*l2norm(Q) ----------------
__global__ __launch_bounds__(256) void epilogue_kernel(float* __restrict__ accout,
                                                       const float* __restrict__ P,
                                                       const float* __restrict__ Q, int nrows) {
  const int lane = threadIdx.x & 63;
  const int wv = threadIdx.x >> 6;
  const int r = blockIdx.x * 4 + wv;
  if (r >= nrows) return;
  const size_t o = (size_t)r * 64 + lane;
  const float av = accout[o];
  const float p = P[o], q = Q[o];
  float pn = wave_sum64(p * p);
  float qn = wave_sum64(q * q);
  pn = fmaxf(sqrtf(pn), 1e-12f);
  qn = fmaxf(sqrtf(qn), 1e-12f);
  accout[o] = av / 3.0f + 0.55f * (p / pn) + 0.55f * (q / qn);
}

extern "C" void kernel_launch(void* const* d_in, const int* in_sizes, int n_in,
                              void* d_out, int out_size, void* d_ws, size_t ws_size,
                              hipStream_t stream) {
  const float* image_feats = (const float*)d_in[0];
  const float* text_feats = (const float*)d_in[1];
  const float* user_emb = (const float*)d_in[2];
  const float* item_emb = (const float*)d_in[3];
  const float* W_img = (const float*)d_in[4];
  const float* b_img = (const float*)d_in[5];
  const float* W_txt = (const float*)d_in[6];
  const float* b_txt = (const float*)d_in[7];
  const float* val_ui = (const float*)d_in[8];
  const float* val_iu = (const float*)d_in[9];
  const int* edge_u = (const int*)d_in[10];
  const int* edge_i = (const int*)d_in[11];

  float* out = (float*)d_out;
  float* u_acc = out + OFF_UOUT;
  float* i_acc = out + OFF_IOUT;
  float* img_item = out + OFF_IIT;
  float* txt_item = out + OFF_TIT;
  float* img_user = out + OFF_IUS;
  float* txt_user = out + OFF_TUS;

  // workspace carve-up (~111 MB total)
  char* wsb = (char*)d_ws;
  size_t off = 0;
  auto take = [&](size_t bytes) -> void* {
    void* p = wsb + off;
    off += (bytes + 255) & ~(size_t)255;
    return p;
  };
  float* feat128 = (float*)take((size_t)N_ITEMS * 128 * 4);  // [item][0:64]=img, [64:128]=txt
  float* i0 = (float*)take((size_t)N_ITEMS * DIM * 4);
  float* i1 = (float*)take((size_t)N_ITEMS * DIM * 4);
  float* u1 = (float*)take((size_t)N_USERS * DIM * 4);
  int* col_u = (int*)take((size_t)N_EDGES * 4);
  float* w_u = (float*)take((size_t)N_EDGES * 4);
  int* col_i = (int*)take((size_t)N_EDGES * 4);
  float* w_i = (float*)take((size_t)N_EDGES * 4);
  int* rs_u = (int*)take((N_USERS + 1) * 4);
  int* cur_u = (int*)take((N_USERS + 1) * 4);
  int* rs_i = (int*)take((N_ITEMS + 1) * 4);
  int* cur_i = (int*)take((N_ITEMS + 1) * 4);
  int* cnt_u = (int*)take((size_t)N_USERS * 4);
  int* cnt_i = (int*)take((size_t)N_ITEMS * 4);
  float* stats = (float*)take(65 * 4);

  hipMemsetAsync(cnt_u, 0, (size_t)N_USERS * 4, stream);
  hipMemsetAsync(cnt_i, 0, (size_t)N_ITEMS * 4, stream);
  hipMemsetAsync(stats, 0, 65 * 4, stream);

  const int eblk = (N_EDGES + 255) / 256;
  hist_kernel<<<eblk, 256, 0, stream>>>(edge_u, edge_i, cnt_u, cnt_i);
  scan_kernel<<<1, 1024, 0, stream>>>(cnt_u, rs_u, cur_u, N_USERS);
  scan_kernel<<<1, 1024, 0, stream>>>(cnt_i, rs_i, cur_i, N_ITEMS);
  fill_kernel<<<eblk, 256, 0, stream>>>(edge_u, edge_i, val_ui, val_iu, cur_u, cur_i,
                                        col_u, w_u, col_i, w_i);

  const int gblk = (N_ITEMS + 127) / 128;
  gemm_kernel<<<2 * gblk, 256, 0, stream>>>(image_feats, W_img, b_img, text_feats, W_txt,
                                            b_txt, feat128);

  stats_kernel<<<2048, 256, 0, stream>>>(user_emb, item_emb, stats);
  finalize_kernel<<<1, 64, 0, stream>>>(stats);
  normalize_kernel<<<2048, 256, 0, stream>>>(user_emb, item_emb, stats, u_acc, i_acc, i0);

  // modal features through the graph
  spmm_dual_kernel<<<N_USERS / 4, 256, 0, stream>>>(rs_u, col_u, w_u, feat128, 128,
                                                    feat128 + 64, 128, img_user, txt_user,
                                                    N_USERS);
  spmm_dual_kernel<<<N_ITEMS / 4, 256, 0, stream>>>(rs_i, col_i, w_i, img_user, 64, txt_user,
                                                    64, img_item, txt_item, N_ITEMS);

  // 2-layer GNN with fused accumulation
  spmm64_kernel<<<N_USERS / 4, 256, 0, stream>>>(rs_u, col_u, w_u, i0, u1, u_acc, N_USERS);
  spmm64_kernel<<<N_ITEMS / 4, 256, 0, stream>>>(rs_i, col_i, w_i, u1, i1, i_acc, N_ITEMS);
  spmm64_kernel<<<N_USERS / 4, 256, 0, stream>>>(rs_u, col_u, w_u, i1, u1, u_acc, N_USERS);
  spmm64_kernel<<<N_ITEMS / 4, 256, 0, stream>>>(rs_i, col_i, w_i, u1, nullptr, i_acc, N_ITEMS);

  epilogue_kernel<<<N_USERS / 4, 256, 0, stream>>>(u_acc, img_user, txt_user, N_USERS);
  epilogue_kernel<<<N_ITEMS / 4, 256, 0, stream>>>(i_acc, img_item, txt_item, N_ITEMS);
}

// Round 2
// 1690.287 us; speedup vs baseline: 1.3646x; 1.3646x over previous
//
#include <hip/hip_runtime.h>
#include <cstdint>
#include <cstddef>

#define N_USERS 100000
#define N_ITEMS 50000
#define DIM     64
#define IMG_D   1024
#define TXT_D   384
#define N_EDGES 2000000
#define N_COMB  (N_USERS + N_ITEMS)

// d_out layout (floats), concatenated in reference return order
#define OFF_UOUT 0
#define OFF_IOUT (N_USERS * DIM)
#define OFF_IIT  (OFF_IOUT + N_ITEMS * DIM)
#define OFF_TIT  (OFF_IIT + N_ITEMS * DIM)
#define OFF_IUS  (OFF_TIT + N_ITEMS * DIM)
#define OFF_TUS  (OFF_IUS + N_USERS * DIM)

typedef __attribute__((ext_vector_type(8))) short short8;
typedef __attribute__((ext_vector_type(4))) float float4v;
typedef __attribute__((ext_vector_type(4))) unsigned int uint4v;

__device__ __forceinline__ float wave_sum64(float v) {
#pragma unroll
  for (int off = 32; off; off >>= 1) v += __shfl_xor(v, off, 64);
  return v;
}

__device__ __forceinline__ unsigned int pack_bf16(float x, float y) {
  // round-to-nearest (ties away); inputs are well-behaved normals
  const unsigned int xu = __float_as_uint(x) + 0x8000u;
  const unsigned int yu = __float_as_uint(y) + 0x8000u;
  return (xu >> 16) | (yu & 0xffff0000u);
}

// ---------------- CSR build ----------------
__global__ __launch_bounds__(256) void hist_kernel(const int* __restrict__ eu,
                                                   const int* __restrict__ ei,
                                                   int* __restrict__ cu, int* __restrict__ ci) {
  const int i = blockIdx.x * 256 + threadIdx.x;
  if (i < N_EDGES) {
    atomicAdd(&cu[eu[i]], 1);
    atomicAdd(&ci[ei[i]], 1);
  }
}

// block 0: users, block 1: items — runs both scans concurrently
__global__ __launch_bounds__(1024) void scan2_kernel(const int* __restrict__ cnt_u,
                                                     int* __restrict__ rs_u, int* __restrict__ cur_u,
                                                     const int* __restrict__ cnt_i,
                                                     int* __restrict__ rs_i, int* __restrict__ cur_i) {
  const int* counts;
  int *rs, *cur, n;
  if (blockIdx.x == 0) { counts = cnt_u; rs = rs_u; cur = cur_u; n = N_USERS; }
  else                 { counts = cnt_i; rs = rs_i; cur = cur_i; n = N_ITEMS; }
  __shared__ int part[1024];
  const int t = threadIdx.x;
  const int chunk = (n + 1023) >> 10;
  const int b = t * chunk;
  const int e = min(b + chunk, n);
  int s = 0;
  for (int j = b; j < e; ++j) s += counts[j];
  part[t] = s;
  __syncthreads();
  for (int off = 1; off < 1024; off <<= 1) {
    const int add = (t >= off) ? part[t - off] : 0;
    __syncthreads();
    part[t] += add;
    __syncthreads();
  }
  int run = (t == 0) ? 0 : part[t - 1];
  for (int j = b; j < e; ++j) {
    rs[j] = run;
    cur[j] = run;
    run += counts[j];
  }
  if (t == 1023) rs[n] = part[1023];
}

__global__ __launch_bounds__(256) void fill_kernel(
    const int* __restrict__ eu, const int* __restrict__ ei,
    const float* __restrict__ vui, const float* __restrict__ viu,
    int* __restrict__ cur_u, int* __restrict__ cur_i,
    int* __restrict__ col_u, float* __restrict__ w_u,
    int* __restrict__ col_i, float* __restrict__ w_i) {
  const int i = blockIdx.x * 256 + threadIdx.x;
  if (i < N_EDGES) {
    const int u = eu[i], it = ei[i];
    const int p = atomicAdd(&cur_u[u], 1);
    col_u[p] = it;
    w_u[p] = vui[i];
    const int q = atomicAdd(&cur_i[it], 1);
    col_i[q] = u;
    w_i[q] = viu[i];
  }
}

// ---------------- W pre-swizzle into MFMA B-fragment layout (bf16) ----------------
// frag(K0idx,n0idx): lane L holds B[k=K0idx*32+(L>>4)*8+j][n=n0idx*16+(L&15)], j=0..7
// stored contiguously: elem index = ((K0idx*4+n0idx)*64 + L)*8 + j
__global__ __launch_bounds__(256) void wswizzle_kernel(const float* __restrict__ Wimg,
                                                       const float* __restrict__ Wtxt,
                                                       unsigned short* __restrict__ WBimg,
                                                       unsigned short* __restrict__ WBtxt) {
  int t = blockIdx.x * 256 + threadIdx.x;
  const float* W;
  unsigned short* WB;
  if (t < 8192) { W = Wimg; WB = WBimg; }
  else if (t < 8192 + 3072) { t -= 8192; W = Wtxt; WB = WBtxt; }
  else return;
  const int frag = t >> 6;
  const int lane = t & 63;
  const int K0idx = frag >> 2;
  const int n0idx = frag & 3;
  const int k0 = K0idx * 32 + ((lane >> 4) << 3);
  const int c = n0idx * 16 + (lane & 15);
  unsigned short us[8];
#pragma unroll
  for (int j = 0; j < 8; ++j) {
    const unsigned int b = __float_as_uint(W[(size_t)(k0 + j) * 64 + c]) + 0x8000u;
    us[j] = (unsigned short)(b >> 16);
  }
  uint4v o;
  o.x = (unsigned int)us[0] | ((unsigned int)us[1] << 16);
  o.y = (unsigned int)us[2] | ((unsigned int)us[3] << 16);
  o.z = (unsigned int)us[4] | ((unsigned int)us[5] << 16);
  o.w = (unsigned int)us[6] | ((unsigned int)us[7] << 16);
  *reinterpret_cast<uint4v*>(WB + (size_t)t * 8) = o;
}

// ---------------- MFMA GEMM: wave = 16 rows x 64 cols, no LDS ----------------
__global__ __launch_bounds__(256) void mfma_gemm_kernel(
    const float* __restrict__ Ximg, const unsigned short* __restrict__ WBimg,
    const float* __restrict__ bimg,
    const float* __restrict__ Xtxt, const unsigned short* __restrict__ WBtxt,
    const float* __restrict__ btxt,
    float* __restrict__ feat128) {
  const int TILES_IMG = N_ITEMS / 16;  // 3125
  const int wv = threadIdx.x >> 6;
  const int lane = threadIdx.x & 63;
  int tile = blockIdx.x * 4 + wv;
  if (tile >= 2 * TILES_IMG) return;

  const float* X;
  const unsigned short* WB;
  const float* bias;
  int K, nK0, c0;
  if (tile < TILES_IMG) { X = Ximg; WB = WBimg; bias = bimg; K = IMG_D; nK0 = IMG_D / 32; c0 = 0; }
  else { tile -= TILES_IMG; X = Xtxt; WB = WBtxt; bias = btxt; K = TXT_D; nK0 = TXT_D / 32; c0 = 64; }

  const int row0 = tile * 16;
  const int m = lane & 15;
  const int koff = (lane >> 4) << 3;
  const float* __restrict__ xp = X + (size_t)(row0 + m) * K + koff;
  const short8* __restrict__ wb8 = reinterpret_cast<const short8*>(WB);

  float4v acc[4];
#pragma unroll
  for (int n0 = 0; n0 < 4; ++n0) acc[n0] = (float4v){0.f, 0.f, 0.f, 0.f};

  for (int K0 = 0; K0 < nK0; ++K0) {
    const float4 xa = *reinterpret_cast<const float4*>(xp + K0 * 32);
    const float4 xb = *reinterpret_cast<const float4*>(xp + K0 * 32 + 4);
    uint4v au;
    au.x = pack_bf16(xa.x, xa.y);
    au.y = pack_bf16(xa.z, xa.w);
    au.z = pack_bf16(xb.x, xb.y);
    au.w = pack_bf16(xb.z, xb.w);
    const short8 af = __builtin_bit_cast(short8, au);
#pragma unroll
    for (int n0 = 0; n0 < 4; ++n0) {
      const short8 bf = wb8[(size_t)(K0 * 4 + n0) * 64 + lane];
      acc[n0] = __builtin_amdgcn_mfma_f32_16x16x32_bf16(af, bf, acc[n0], 0, 0, 0);
    }
  }

  // C/D: col = lane&15, row = (lane>>4)*4 + reg
  const int crow = (lane >> 4) << 2;
  const int ccol = lane & 15;
#pragma unroll
  for (int n0 = 0; n0 < 4; ++n0) {
    const float bv = bias[n0 * 16 + ccol];
#pragma unroll
    for (int r = 0; r < 4; ++r) {
      feat128[(size_t)(row0 + crow + r) * 128 + c0 + n0 * 16 + ccol] = acc[n0][r] + bv;
    }
  }
}

// ---------------- normalization statistics ----------------
__global__ __launch_bounds__(256) void stats_kernel(const float* __restrict__ ue,
                                                    const float* __restrict__ ie,
                                                    float* __restrict__ stats) {
  const int t = threadIdx.x;
  const int lane = t & 63;
  float cs = 0.f, ss = 0.f;
  const size_t total = (size_t)N_COMB * DIM;
  const size_t ubound = (size_t)N_USERS * DIM;
  const size_t stride = (size_t)gridDim.x * blockDim.x;
  for (size_t i = (size_t)blockIdx.x * blockDim.x + t; i < total; i += stride) {
    const float v = (i < ubound) ? ue[i] : ie[i - ubound];
    cs += v;
    ss += v * v;
  }
  ss = wave_sum64(ss);
  __shared__ float lcol[4][64];
  __shared__ float lss[4];
  const int wv = t >> 6;
  lcol[wv][lane] = cs;
  if (lane == 0) lss[wv] = ss;
  __syncthreads();
  if (wv == 0) {
    const float c = lcol[0][lane] + lcol[1][lane] + lcol[2][lane] + lcol[3][lane];
    atomicAdd(&stats[lane], c);
    if (lane == 0) atomicAdd(&stats[64], lss[0] + lss[1] + lss[2] + lss[3]);
  }
}

__global__ void finalize_kernel(float* __restrict__ stats) {
  const int d = threadIdx.x;  // 64 threads
  const float ssum = stats[64];
  const float m = stats[d] / (float)N_COMB;
  const float m2sum = wave_sum64(m * m);
  const float tot = ssum - (float)N_COMB * m2sum;
  const float rnm = sqrtf(tot / (float)N_COMB + 1e-6f);
  stats[d] = m;
  if (d == 0) stats[64] = 1.f / rnm;
}

__global__ __launch_bounds__(256) void normalize_kernel(
    const float* __restrict__ ue, const float* __restrict__ ie, const float* __restrict__ stats,
    float* __restrict__ uacc, float* __restrict__ iacc, float* __restrict__ i0) {
  const int lane = threadIdx.x & 63;
  const float m = stats[lane];
  const float inv = stats[64];
  const size_t total = (size_t)N_COMB * DIM;
  const size_t ubound = (size_t)N_USERS * DIM;
  const size_t stride = (size_t)gridDim.x * blockDim.x;
  for (size_t i = (size_t)blockIdx.x * blockDim.x + threadIdx.x; i < total; i += stride) {
    if (i < ubound) {
      uacc[i] = (ue[i] - m) * inv;
    } else {
      const size_t j = i - ubound;
      const float v = (ie[j] - m) * inv;
      iacc[j] = v;
      i0[j] = v;
    }
  }
}

// ---------------- triple SPMM: {O1,O2,O3} = A @ {X1,X2,X3}; acc += O3 ----------------
__global__ __launch_bounds__(256) void spmm_triple_kernel(
    const int* __restrict__ rs, const int* __restrict__ col, const float* __restrict__ w,
    const float* __restrict__ X1, int s1, const float* __restrict__ X2, int s2,
    const float* __restrict__ X3, int s3,
    float* __restrict__ O1, float* __restrict__ O2, float* __restrict__ O3,
    float* __restrict__ acc, int nrows) {
  const int lane = threadIdx.x & 63;
  const int wv = __builtin_amdgcn_readfirstlane(threadIdx.x >> 6);
  const int r = blockIdx.x * 4 + wv;
  if (r >= nrows) return;
  const int s = rs[r], e = rs[r + 1];
  float a1 = 0.f, a2 = 0.f, a3 = 0.f;
  int k = s;
  for (; k + 2 <= e; k += 2) {
    const int c0 = col[k], c1 = col[k + 1];
    const float w0 = w[k], w1 = w[k + 1];
    const float p10 = X1[(size_t)c0 * s1 + lane];
    const float p20 = X2[(size_t)c0 * s2 + lane];
    const float p30 = X3[(size_t)c0 * s3 + lane];
    const float p11 = X1[(size_t)c1 * s1 + lane];
    const float p21 = X2[(size_t)c1 * s2 + lane];
    const float p31 = X3[(size_t)c1 * s3 + lane];
    a1 = fmaf(w0, p10, a1);
    a2 = fmaf(w0, p20, a2);
    a3 = fmaf(w0, p30, a3);
    a1 = fmaf(w1, p11, a1);
    a2 = fmaf(w1, p21, a2);
    a3 = fmaf(w1, p31, a3);
  }
  for (; k < e; ++k) {
    const int c = col[k];
    const float wk = w[k];
    a1 = fmaf(wk, X1[(size_t)c * s1 + lane], a1);
    a2 = fmaf(wk, X2[(size_t)c * s2 + lane], a2);
    a3 = fmaf(wk, X3[(size_t)c * s3 + lane], a3);
  }
  const size_t o = (size_t)r * 64 + lane;
  O1[o] = a1;
  O2[o] = a2;
  O3[o] = a3;
  acc[o] += a3;
}

// ---------------- final SPMM + fused epilogue ----------------
// a = (A @ X)[r]; if(O) O[r]=a; accio[r] = (accio[r]+a)/3 + .55*l2n(P[r]) + .55*l2n(Q[r])
__global__ __launch_bounds__(256) void spmm_final_kernel(
    const int* __restrict__ rs, const int* __restrict__ col, const float* __restrict__ w,
    const float* __restrict__ X, float* __restrict__ O,
    const float* __restrict__ P, const float* __restrict__ Q,
    float* __restrict__ accio, int nrows) {
  const int lane = threadIdx.x & 63;
  const int wv = __builtin_amdgcn_readfirstlane(threadIdx.x >> 6);
  const int r = blockIdx.x * 4 + wv;
  if (r >= nrows) return;
  const int s = rs[r], e = rs[r + 1];
  float a = 0.f;
  int k = s;
  for (; k + 4 <= e; k += 4) {
    const int c0 = col[k], c1 = col[k + 1], c2 = col[k + 2], c3 = col[k + 3];
    const float w0 = w[k], w1 = w[k + 1], w2 = w[k + 2], w3 = w[k + 3];
    const float x0 = X[(size_t)c0 * 64 + lane];
    const float x1 = X[(size_t)c1 * 64 + lane];
    const float x2 = X[(size_t)c2 * 64 + lane];
    const float x3 = X[(size_t)c3 * 64 + lane];
    a = fmaf(w0, x0, a);
    a = fmaf(w1, x1, a);
    a = fmaf(w2, x2, a);
    a = fmaf(w3, x3, a);
  }
  for (; k < e; ++k) a = fmaf(w[k], X[(size_t)col[k] * 64 + lane], a);
  const size_t o = (size_t)r * 64 + lane;
  if (O) O[o] = a;
  const float p = P[o], q = Q[o];
  float pn = wave_sum64(p * p);
  float qn = wave_sum64(q * q);
  pn = fmaxf(sqrtf(pn), 1e-12f);
  qn = fmaxf(sqrtf(qn), 1e-12f);
  accio[o] = (accio[o] + a) * (1.0f / 3.0f) + 0.55f * (p / pn) + 0.55f * (q / qn);
}

extern "C" void kernel_launch(void* const* d_in, const int* in_sizes, int n_in,
                              void* d_out, int out_size, void* d_ws, size_t ws_size,
                              hipStream_t stream) {
  const float* image_feats = (const float*)d_in[0];
  const float* text_feats = (const float*)d_in[1];
  const float* user_emb = (const float*)d_in[2];
  const float* item_emb = (const float*)d_in[3];
  const float* W_img = (const float*)d_in[4];
  const float* b_img = (const float*)d_in[5];
  const float* W_txt = (const float*)d_in[6];
  const float* b_txt = (const float*)d_in[7];
  const float* val_ui = (const float*)d_in[8];
  const float* val_iu = (const float*)d_in[9];
  const int* edge_u = (const int*)d_in[10];
  const int* edge_i = (const int*)d_in[11];

  float* out = (float*)d_out;
  float* u_acc = out + OFF_UOUT;
  float* i_acc = out + OFF_IOUT;
  float* img_item = out + OFF_IIT;
  float* txt_item = out + OFF_TIT;
  float* img_user = out + OFF_IUS;
  float* txt_user = out + OFF_TUS;

  // workspace carve-up (~111 MB)
  char* wsb = (char*)d_ws;
  size_t off = 0;
  auto take = [&](size_t bytes) -> void* {
    void* p = wsb + off;
    off += (bytes + 255) & ~(size_t)255;
    return p;
  };
  float* feat128 = (float*)take((size_t)N_ITEMS * 128 * 4);  // [item][0:64]=img, [64:128]=txt
  float* i0 = (float*)take((size_t)N_ITEMS * DIM * 4);
  float* i1 = (float*)take((size_t)N_ITEMS * DIM * 4);
  float* u1 = (float*)take((size_t)N_USERS * DIM * 4);       // layer-1 users, then reused for u2
  int* col_u = (int*)take((size_t)N_EDGES * 4);
  float* w_u = (float*)take((size_t)N_EDGES * 4);
  int* col_i = (int*)take((size_t)N_EDGES * 4);
  float* w_i = (float*)take((size_t)N_EDGES * 4);
  int* rs_u = (int*)take((N_USERS + 1) * 4);
  int* cur_u = (int*)take((N_USERS + 1) * 4);
  int* rs_i = (int*)take((N_ITEMS + 1) * 4);
  int* cur_i = (int*)take((N_ITEMS + 1) * 4);
  int* cnt_u = (int*)take((size_t)N_USERS * 4);
  int* cnt_i = (int*)take((size_t)N_ITEMS * 4);
  unsigned short* WBimg = (unsigned short*)take((size_t)8192 * 8 * 2);  // 128 KB
  unsigned short* WBtxt = (unsigned short*)take((size_t)3072 * 8 * 2);  // 48 KB
  float* stats = (float*)take(65 * 4);

  hipMemsetAsync(cnt_u, 0, (size_t)N_USERS * 4, stream);
  hipMemsetAsync(cnt_i, 0, (size_t)N_ITEMS * 4, stream);
  hipMemsetAsync(stats, 0, 65 * 4, stream);

  const int eblk = (N_EDGES + 255) / 256;
  hist_kernel<<<eblk, 256, 0, stream>>>(edge_u, edge_i, cnt_u, cnt_i);
  scan2_kernel<<<2, 1024, 0, stream>>>(cnt_u, rs_u, cur_u, cnt_i, rs_i, cur_i);
  fill_kernel<<<eblk, 256, 0, stream>>>(edge_u, edge_i, val_ui, val_iu, cur_u, cur_i,
                                        col_u, w_u, col_i, w_i);

  wswizzle_kernel<<<44, 256, 0, stream>>>(W_img, W_txt, WBimg, WBtxt);
  const int ntiles = 2 * (N_ITEMS / 16);  // 6250
  mfma_gemm_kernel<<<(ntiles + 3) / 4, 256, 0, stream>>>(image_feats, WBimg, b_img,
                                                         text_feats, WBtxt, b_txt, feat128);

  stats_kernel<<<2048, 256, 0, stream>>>(user_emb, item_emb, stats);
  finalize_kernel<<<1, 64, 0, stream>>>(stats);
  normalize_kernel<<<2048, 256, 0, stream>>>(user_emb, item_emb, stats, u_acc, i_acc, i0);

  // user side: img_user/txt_user/u1 in one pass; u_acc += u1
  spmm_triple_kernel<<<N_USERS / 4, 256, 0, stream>>>(
      rs_u, col_u, w_u, feat128, 128, feat128 + 64, 128, i0, 64,
      img_user, txt_user, u1, u_acc, N_USERS);
  // item side: img_item/txt_item/i1 in one pass; i_acc += i1
  spmm_triple_kernel<<<N_ITEMS / 4, 256, 0, stream>>>(
      rs_i, col_i, w_i, img_user, 64, txt_user, 64, u1, 64,
      img_item, txt_item, i1, i_acc, N_ITEMS);
  // u2 = A_ui @ i1 (stored into u1 buffer) + fused user epilogue
  spmm_final_kernel<<<N_USERS / 4, 256, 0, stream>>>(
      rs_u, col_u, w_u, i1, u1, img_user, txt_user, u_acc, N_USERS);
  // i2 = A_iu @ u2 + fused item epilogue
  spmm_final_kernel<<<N_ITEMS / 4, 256, 0, stream>>>(
      rs_i, col_i, w_i, u1, nullptr, img_item, txt_item, i_acc, N_ITEMS);
}